// Round 12
// baseline (198.800 us; speedup 1.0000x reference)
//
#include <hip/hip_runtime.h>
#include <stddef.h>

#define N_NODES 10000
#define N_EDGES 160000
#define DIM     512
#define RBT     158           // 64-row tiles incl. one zero pad tile (10112 rows)
#define RB128   79            // 128-row blocks
#define GBLKS   (RB128 * 4)   // 316 gemm blocks
#define SCAN_BLKS 40
#define EBLKS   625

typedef short bf16x8 __attribute__((ext_vector_type(8)));
typedef float f32x4  __attribute__((ext_vector_type(4)));

__device__ inline unsigned short bf16_rne(float f) {
    unsigned u = __builtin_bit_cast(unsigned, f);
    u += 0x7FFF + ((u >> 16) & 1);
    return (unsigned short)(u >> 16);
}
__device__ inline float bf16_to_f32(unsigned short h) {
    unsigned u = ((unsigned)h) << 16;
    return __builtin_bit_cast(float, u);
}

__device__ inline void gld_lds16(const void* g, void* lds) {
    __builtin_amdgcn_global_load_lds(
        (const __attribute__((address_space(1))) void*)g,
        (__attribute__((address_space(3))) void*)lds, 16, 0, 0);
}

// ================= pack weights + zero deg =================
// Tile layout (shorts): [colblk64][kt 16][arr 2][col 64][k 32]; XOR perm baked.

__global__ __launch_bounds__(256) void packw_zero_kernel(
    const float* __restrict__ W1, const float* __restrict__ W2,
    const float* __restrict__ Wp1, const float* __restrict__ Wp2,
    short* __restrict__ T1, short* __restrict__ T2,
    short* __restrict__ Tp1, short* __restrict__ Tp2,
    int* __restrict__ deg) {
    const int bid = blockIdx.x;
    if (bid >= 512) {
        int i = (bid - 512) * 256 + threadIdx.x;
        if (i < N_NODES) deg[i] = 0;
        return;
    }
    const int wsel = bid >> 7;
    const float* W = (wsel == 0) ? W1 : (wsel == 1) ? W2 : (wsel == 2) ? Wp1 : Wp2;
    short* WT      = (wsel == 0) ? T1 : (wsel == 1) ? T2 : (wsel == 2) ? Tp1 : Tp2;
    int id = (bid & 127) * 256 + threadIdx.x;
    int n  = id & 511;
    int kc = id >> 9;
    int colblk = n >> 6, col = n & 63;
    int kt = kc >> 2, kq = kc & 3;
    short hi[8], lo[8];
#pragma unroll
    for (int j = 0; j < 8; ++j) {
        float v = W[(size_t)(kc * 8 + j) * 512 + n];
        unsigned short h = bf16_rne(v);
        hi[j] = (short)h;
        lo[j] = (short)bf16_rne(v - bf16_to_f32(h));
    }
    size_t base = (size_t)(colblk * 16 + kt) * 4096 + col * 32 + ((kq ^ ((col >> 1) & 3)) << 3);
    *(int4*)(WT + base)        = *(const int4*)hi;
    *(int4*)(WT + base + 2048) = *(const int4*)lo;
}

// ================= pack x + count_deg =================

__global__ __launch_bounds__(256) void packa_count_kernel(
    const float* __restrict__ A, short* __restrict__ P0,
    const int* __restrict__ ei, int* __restrict__ deg) {
    const int bid = blockIdx.x;
    if (bid >= RBT * 16) {
        int e = (bid - RBT * 16) * 256 + threadIdx.x;
        if (e < N_EDGES) atomicAdd(&deg[ei[N_EDGES + e]], 1);
        return;
    }
    const int kt = bid & 15;
    const int rb = bid >> 4;
    const int t  = threadIdx.x;
    const int r  = t >> 2;
    const int kq = t & 3;
    const int row = rb * 64 + r;
    float v[8] = {};
    if (row < N_NODES) {
        float4 a = *(const float4*)(A + (size_t)row * 512 + kt * 32 + kq * 8);
        float4 b = *(const float4*)(A + (size_t)row * 512 + kt * 32 + kq * 8 + 4);
        v[0]=a.x; v[1]=a.y; v[2]=a.z; v[3]=a.w; v[4]=b.x; v[5]=b.y; v[6]=b.z; v[7]=b.w;
    }
    size_t base = (size_t)(rb * 16 + kt) * 4096 + r * 32 + ((kq ^ ((r >> 1) & 3)) << 3);
    short hi[8], lo[8];
#pragma unroll
    for (int j = 0; j < 8; ++j) {
        unsigned short h = bf16_rne(v[j]);
        hi[j] = (short)h;
        lo[j] = (short)bf16_rne(v[j] - bf16_to_f32(h));
    }
    *(int4*)(P0 + base)        = *(const int4*)hi;
    *(int4*)(P0 + base + 2048) = *(const int4*)lo;
}

// ================= scans (verified) =================

__global__ __launch_bounds__(256) void scan1_kernel(const int* __restrict__ deg,
                                                    int* __restrict__ row_off,
                                                    int* __restrict__ bsum,
                                                    float* __restrict__ dis,
                                                    int* __restrict__ cursor, int n) {
    __shared__ int sm[256];
    const int i = blockIdx.x * 256 + threadIdx.x;
    int v = (i < n) ? deg[i] : 0;
    if (i < n) {
        dis[i] = rsqrtf((float)(v + 1));
        cursor[i] = 0;
    }
    sm[threadIdx.x] = v;
    __syncthreads();
    for (int off = 1; off < 256; off <<= 1) {
        int t = (threadIdx.x >= (unsigned)off) ? sm[threadIdx.x - off] : 0;
        __syncthreads();
        sm[threadIdx.x] += t;
        __syncthreads();
    }
    if (i < n) row_off[i + 1] = sm[threadIdx.x];
    if (threadIdx.x == 255) bsum[blockIdx.x] = sm[255];
}

__global__ __launch_bounds__(64) void scan2_kernel(int* __restrict__ bsum) {
    const int lane = threadIdx.x;
    int v0 = (lane < SCAN_BLKS) ? bsum[lane] : 0;
    int v = v0;
    for (int off = 1; off < 64; off <<= 1) {
        int t = __shfl_up(v, off, 64);
        if (lane >= off) v += t;
    }
    if (lane < SCAN_BLKS) bsum[lane] = v - v0;
}

__global__ __launch_bounds__(256) void scan3_kernel(int* __restrict__ row_off,
                                                    const int* __restrict__ bsum, int n) {
    const int i = blockIdx.x * 256 + threadIdx.x;
    if (i < n) row_off[i + 1] += bsum[blockIdx.x];
    if (i == 0) row_off[0] = 0;
}

// ================= 128x128 LDS-staged GEMM core =================
// 4 waves (2x2), glds double-buffer, counted vmcnt(8) across raw s_barrier:
// the next tile's 8 loads/wave stay in flight through the MFMA phase.
// cb-major bijective XCD chunking: each XCD's ~40 blocks share one B-panel (L2-hot).

__device__ __forceinline__ void map_block(int bid, int& rb, int& cb) {
    const int q = GBLKS / 8;      // 39
    const int r = GBLKS % 8;      // 4
    int xcd = bid & 7;
    int idx = bid >> 3;
    int L = (xcd < r ? xcd * (q + 1) : r * (q + 1) + (xcd - r) * q) + idx;
    cb = L / RB128;
    rb = L - cb * RB128;
}

__device__ __forceinline__ void gemm128_core(
    const short* __restrict__ Apk, const short* __restrict__ Wpk,
    int bid, f32x4 (&acc)[4][4],
    short (*As)[8192], short (*Bs)[8192],
    int& rb, int& cb, int& wr, int& wc)
{
    map_block(bid, rb, cb);
    const int tid = threadIdx.x;
    const int w = tid >> 6;
    wr = w >> 1;
    wc = w & 1;
    const int lane = tid & 63;
    const int l15 = lane & 15, kg = lane >> 4;
    const int kso = ((kg ^ ((l15 >> 1) & 3)) << 3);
    const int wofs = w * 1024;

    const char* At0 = (const char*)(Apk + (size_t)(rb * 2)     * 16 * 4096);
    const char* At1 = (const char*)(Apk + (size_t)(rb * 2 + 1) * 16 * 4096);
    const char* Bt0 = (const char*)(Wpk + (size_t)(cb * 2)     * 16 * 4096);
    const char* Bt1 = (const char*)(Wpk + (size_t)(cb * 2 + 1) * 16 * 4096);

#pragma unroll
    for (int i = 0; i < 4; ++i)
#pragma unroll
        for (int j = 0; j < 4; ++j) acc[i][j] = (f32x4){0.f, 0.f, 0.f, 0.f};

    // 8 glds per wave per stage
    auto stage = [&](int buf, int kt) {
        const int tb = kt * 8192;
        char* ad = (char*)&As[buf][0];
        char* bd = (char*)&Bs[buf][0];
#pragma unroll
        for (int ii = 0; ii < 2; ++ii) {
            const int go = tb + ii * 4096 + tid * 16;
            const int lo_ = ii * 4096 + wofs;
            gld_lds16(At0 + go, ad + lo_);
            gld_lds16(At1 + go, ad + 8192 + lo_);
            gld_lds16(Bt0 + go, bd + lo_);
            gld_lds16(Bt1 + go, bd + 8192 + lo_);
        }
    };

    stage(0, 0);

#pragma unroll
    for (int kt = 0; kt < 16; ++kt) {
        const int buf = kt & 1;
        if (kt < 15) {
            stage(buf ^ 1, kt + 1);
            asm volatile("s_waitcnt vmcnt(8)" ::: "memory");   // tile kt landed; kt+1 in flight
        } else {
            asm volatile("s_waitcnt vmcnt(0)" ::: "memory");
        }
        __builtin_amdgcn_s_barrier();                          // B1: all waves' tile kt visible
        __builtin_amdgcn_sched_barrier(0);

        const short* as = &As[buf][wr * 4096];
        const short* bs = &Bs[buf][wc * 4096];
        bf16x8 af[4][2], bf[4][2];
#pragma unroll
        for (int m = 0; m < 4; ++m) {
            const int ro = (m * 16 + l15) * 32 + kso;
            af[m][0] = *(const bf16x8*)&as[ro];
            af[m][1] = *(const bf16x8*)&as[2048 + ro];
        }
#pragma unroll
        for (int n = 0; n < 4; ++n) {
            const int co = (n * 16 + l15) * 32 + kso;
            bf[n][0] = *(const bf16x8*)&bs[co];
            bf[n][1] = *(const bf16x8*)&bs[2048 + co];
        }
#pragma unroll
        for (int m = 0; m < 4; ++m)
#pragma unroll
            for (int n = 0; n < 4; ++n) {
                acc[m][n] = __builtin_amdgcn_mfma_f32_16x16x32_bf16(af[m][0], bf[n][0], acc[m][n], 0, 0, 0);
                acc[m][n] = __builtin_amdgcn_mfma_f32_16x16x32_bf16(af[m][0], bf[n][1], acc[m][n], 0, 0, 0);
                acc[m][n] = __builtin_amdgcn_mfma_f32_16x16x32_bf16(af[m][1], bf[n][0], acc[m][n], 0, 0, 0);
            }
        __builtin_amdgcn_sched_barrier(0);
        __builtin_amdgcn_s_barrier();                          // B2: readers done before overwrite
    }
}

// ---- epilogues (each wave writes its own 64x64 quarter) ----

template<bool RELU_OUT>
__device__ __forceinline__ void epi128_f32(f32x4 (&acc)[4][4], const float* bias,
                                           float* C, int rb, int cb, int wr, int wc) {
    const int lane = threadIdx.x & 63;
    const int l15 = lane & 15, kg = lane >> 4;
#pragma unroll
    for (int n = 0; n < 4; ++n) {
        int c = cb * 128 + wc * 64 + n * 16 + l15;
        float bv = bias[c];
#pragma unroll
        for (int m = 0; m < 4; ++m) {
            int r0 = rb * 128 + wr * 64 + m * 16 + kg * 4;
#pragma unroll
            for (int j = 0; j < 4; ++j) {
                int row = r0 + j;
                if (row < N_NODES) {
                    float v = acc[m][n][j] + bv;
                    if (RELU_OUT) v = fmaxf(v, 0.f);
                    C[(size_t)row * 512 + c] = v;
                }
            }
        }
    }
}

__device__ __forceinline__ void epi128_bf16(f32x4 (&acc)[4][4], const float* bias,
                                            unsigned short* C, int rb, int cb, int wr, int wc) {
    const int lane = threadIdx.x & 63;
    const int l15 = lane & 15, kg = lane >> 4;
#pragma unroll
    for (int n = 0; n < 4; ++n) {
        int c = cb * 128 + wc * 64 + n * 16 + l15;
        float bv = bias[c];
#pragma unroll
        for (int m = 0; m < 4; ++m) {
            int r0 = rb * 128 + wr * 64 + m * 16 + kg * 4;
#pragma unroll
            for (int j = 0; j < 4; ++j) {
                int row = r0 + j;
                if (row < N_NODES)
                    C[(size_t)row * 512 + c] = bf16_rne(acc[m][n][j] + bv);
            }
        }
    }
}

// relu(acc+bias) -> packed A-layout (hi/lo row-tiles) for the next GEMM
__device__ __forceinline__ void epi128_pack(f32x4 (&acc)[4][4], const float* bias,
                                            short* Cpk, int rb, int cb, int wr, int wc) {
    const int lane = threadIdx.x & 63;
    const int l15 = lane & 15, kg = lane >> 4;
#pragma unroll
    for (int n = 0; n < 4; ++n) {
        int c = cb * 128 + wc * 64 + n * 16 + l15;   // = next-gemm k index
        int kt_n = c >> 5, kk = c & 31, kgn = kk >> 3, kj = kk & 7;
        float bv = bias[c];
#pragma unroll
        for (int m = 0; m < 4; ++m) {
#pragma unroll
            for (int j = 0; j < 4; ++j) {
                int grow = rb * 128 + wr * 64 + m * 16 + kg * 4 + j;   // <= 10111
                float v = (grow < N_NODES) ? fmaxf(acc[m][n][j] + bv, 0.f) : 0.f;
                unsigned short h = bf16_rne(v);
                unsigned short l = bf16_rne(v - bf16_to_f32(h));
                int rt = grow >> 6, rl = grow & 63;
                size_t dst = (size_t)(rt * 16 + kt_n) * 4096 + rl * 32
                           + ((kgn ^ ((rl >> 1) & 3)) << 3) + kj;
                Cpk[dst]        = (short)h;
                Cpk[dst + 2048] = (short)l;
            }
        }
    }
}

// ================= fused GEMM1 + scatter =================

__global__ __launch_bounds__(256, 2) void gemm1_scatter_kernel(
    const short* __restrict__ APKx, const short* __restrict__ WT1,
    const float* __restrict__ b1, unsigned short* __restrict__ Hb,
    const int* __restrict__ ei, const float* __restrict__ dis,
    const int* __restrict__ row_off, int* __restrict__ cursor,
    int* __restrict__ csr_src, float* __restrict__ csr_norm)
{
    __shared__ short As[2][8192];
    __shared__ short Bs[2][8192];
    const int bid = blockIdx.x;
    if (bid >= GBLKS) {
        int e = (bid - GBLKS) * 256 + threadIdx.x;
        if (e < N_EDGES) {
            int s = ei[e];
            int d = ei[N_EDGES + e];
            int slot = row_off[d] + atomicAdd(&cursor[d], 1);
            csr_src[slot]  = s;
            csr_norm[slot] = dis[s] * dis[d];
        }
        return;
    }
    f32x4 acc[4][4];
    int rb, cb, wr, wc;
    gemm128_core(APKx, WT1, bid, acc, As, Bs, rb, cb, wr, wc);
    epi128_bf16(acc, b1, Hb, rb, cb, wr, wc);
}

// ================= aggregate1 + fused z-pack (grid 10112) =================

__global__ __launch_bounds__(256) void agg1_pack_kernel(
    const unsigned short* __restrict__ Hb,
    const float* __restrict__ dis,
    const int* __restrict__ row_off,
    const int* __restrict__ csr_src,
    const float* __restrict__ csr_norm,
    float* __restrict__ z,
    short* __restrict__ ZPKp, short* __restrict__ ZPKr)
{
    const int node = blockIdx.x;
    const int t = threadIdx.x;
    const int f0 = 2 * t;
    const int kt = f0 >> 5, kq = (f0 >> 3) & 3, j = f0 & 7;
    const int rb = node >> 6, r = node & 63;
    const size_t dst = (size_t)(rb * 16 + kt) * 4096 + r * 32 + ((kq ^ ((r >> 1) & 3)) << 3) + j;

    if (node >= N_NODES) {
        ushort2 zz = make_ushort2(0, 0);
        *(ushort2*)(ZPKp + dst)        = zz;
        *(ushort2*)(ZPKp + dst + 2048) = zz;
        *(ushort2*)(ZPKr + dst)        = zz;
        *(ushort2*)(ZPKr + dst + 2048) = zz;
        return;
    }

    const int start = row_off[node];
    const int end   = row_off[node + 1];
    const float dn = dis[node];
    const float sw = dn * dn;

    ushort2 hv = *((const ushort2*)(Hb + (size_t)node * DIM) + t);
    float a0 = bf16_to_f32(hv.x) * sw;
    float a1 = bf16_to_f32(hv.y) * sw;

    int e = start;
    for (; e + 3 < end; e += 4) {
        int s0 = csr_src[e],     s1 = csr_src[e + 1];
        int s2 = csr_src[e + 2], s3 = csr_src[e + 3];
        float w0 = csr_norm[e],     w1 = csr_norm[e + 1];
        float w2 = csr_norm[e + 2], w3 = csr_norm[e + 3];
        ushort2 v0 = *((const ushort2*)(Hb + (size_t)s0 * DIM) + t);
        ushort2 v1 = *((const ushort2*)(Hb + (size_t)s1 * DIM) + t);
        ushort2 v2 = *((const ushort2*)(Hb + (size_t)s2 * DIM) + t);
        ushort2 v3 = *((const ushort2*)(Hb + (size_t)s3 * DIM) + t);
        a0 += bf16_to_f32(v0.x) * w0 + bf16_to_f32(v1.x) * w1
            + bf16_to_f32(v2.x) * w2 + bf16_to_f32(v3.x) * w3;
        a1 += bf16_to_f32(v0.y) * w0 + bf16_to_f32(v1.y) * w1
            + bf16_to_f32(v2.y) * w2 + bf16_to_f32(v3.y) * w3;
    }
    for (; e < end; ++e) {
        int s = csr_src[e];
        float w = csr_norm[e];
        ushort2 v = *((const ushort2*)(Hb + (size_t)s * DIM) + t);
        a0 += bf16_to_f32(v.x) * w;
        a1 += bf16_to_f32(v.y) * w;
    }
    *((float2*)(z + (size_t)node * DIM) + t) = make_float2(a0, a1);

    unsigned short h0 = bf16_rne(a0), h1 = bf16_rne(a1);
    *(ushort2*)(ZPKp + dst)        = make_ushort2(h0, h1);
    *(ushort2*)(ZPKp + dst + 2048) = make_ushort2(bf16_rne(a0 - bf16_to_f32(h0)),
                                                  bf16_rne(a1 - bf16_to_f32(h1)));
    float r0 = fmaxf(a0, 0.f), r1 = fmaxf(a1, 0.f);
    unsigned short g0 = bf16_rne(r0), g1 = bf16_rne(r1);
    *(ushort2*)(ZPKr + dst)        = make_ushort2(g0, g1);
    *(ushort2*)(ZPKr + dst + 2048) = make_ushort2(bf16_rne(r0 - bf16_to_f32(g0)),
                                                  bf16_rne(r1 - bf16_to_f32(g1)));
}

// ================= fused GEMM2 || GEMM3 =================

__global__ __launch_bounds__(256, 2) void gemm23_kernel(
    const short* __restrict__ ZPKr, const short* __restrict__ WT2,
    const float* __restrict__ b2, unsigned short* __restrict__ Hb,
    const short* __restrict__ ZPKp, const short* __restrict__ WTp1,
    const float* __restrict__ bp1, short* __restrict__ APKp1)
{
    __shared__ short As[2][8192];
    __shared__ short Bs[2][8192];
    const int bid = blockIdx.x;
    f32x4 acc[4][4];
    int rb, cb, wr, wc;
    if (bid < GBLKS) {
        gemm128_core(ZPKr, WT2, bid, acc, As, Bs, rb, cb, wr, wc);
        epi128_bf16(acc, b2, Hb, rb, cb, wr, wc);
    } else {
        gemm128_core(ZPKp, WTp1, bid - GBLKS, acc, As, Bs, rb, cb, wr, wc);
        epi128_pack(acc, bp1, APKp1, rb, cb, wr, wc);
    }
}

// ================= aggregate2 =================

__global__ __launch_bounds__(256) void agg2_kernel(
    const unsigned short* __restrict__ Hb, const float* __restrict__ dis,
    const int* __restrict__ row_off, const int* __restrict__ csr_src,
    const float* __restrict__ csr_norm, float* __restrict__ out)
{
    const int node = blockIdx.x;
    const int t = threadIdx.x;
    const int start = row_off[node];
    const int end   = row_off[node + 1];
    const float dn = dis[node];
    const float sw = dn * dn;

    ushort2 hv = *((const ushort2*)(Hb + (size_t)node * DIM) + t);
    float a0 = bf16_to_f32(hv.x) * sw;
    float a1 = bf16_to_f32(hv.y) * sw;

    int e = start;
    for (; e + 3 < end; e += 4) {
        int s0 = csr_src[e],     s1 = csr_src[e + 1];
        int s2 = csr_src[e + 2], s3 = csr_src[e + 3];
        float w0 = csr_norm[e],     w1 = csr_norm[e + 1];
        float w2 = csr_norm[e + 2], w3 = csr_norm[e + 3];
        ushort2 v0 = *((const ushort2*)(Hb + (size_t)s0 * DIM) + t);
        ushort2 v1 = *((const ushort2*)(Hb + (size_t)s1 * DIM) + t);
        ushort2 v2 = *((const ushort2*)(Hb + (size_t)s2 * DIM) + t);
        ushort2 v3 = *((const ushort2*)(Hb + (size_t)s3 * DIM) + t);
        a0 += bf16_to_f32(v0.x) * w0 + bf16_to_f32(v1.x) * w1
            + bf16_to_f32(v2.x) * w2 + bf16_to_f32(v3.x) * w3;
        a1 += bf16_to_f32(v0.y) * w0 + bf16_to_f32(v1.y) * w1
            + bf16_to_f32(v2.y) * w2 + bf16_to_f32(v3.y) * w3;
    }
    for (; e < end; ++e) {
        int s = csr_src[e];
        float w = csr_norm[e];
        ushort2 v = *((const ushort2*)(Hb + (size_t)s * DIM) + t);
        a0 += bf16_to_f32(v.x) * w;
        a1 += bf16_to_f32(v.y) * w;
    }
    *((float2*)(out + (size_t)node * DIM) + t) = make_float2(a0, a1);
}

// ================= GEMM4 =================

__global__ __launch_bounds__(256, 2) void gemm4_kernel(
    const short* __restrict__ APKp1, const short* __restrict__ WTp2,
    const float* __restrict__ bp2, float* __restrict__ proj)
{
    __shared__ short As[2][8192];
    __shared__ short Bs[2][8192];
    f32x4 acc[4][4];
    int rb, cb, wr, wc;
    gemm128_core(APKp1, WTp2, blockIdx.x, acc, As, Bs, rb, cb, wr, wc);
    epi128_f32<false>(acc, bp2, proj, rb, cb, wr, wc);
}

// ================= launch =================

extern "C" void kernel_launch(void* const* d_in, const int* in_sizes, int n_in,
                              void* d_out, int out_size, void* d_ws, size_t ws_size,
                              hipStream_t stream) {
    const float* x   = (const float*)d_in[0];
    const int*   ei  = (const int*)d_in[1];
    const float* W1  = (const float*)d_in[2];
    const float* b1  = (const float*)d_in[3];
    const float* W2  = (const float*)d_in[4];
    const float* b2  = (const float*)d_in[5];
    const float* Wp1 = (const float*)d_in[6];
    const float* bp1 = (const float*)d_in[7];
    const float* Wp2 = (const float*)d_in[8];
    const float* bp2 = (const float*)d_in[9];

    float* out  = (float*)d_out;
    float* z    = out + (size_t)N_NODES * DIM;
    float* proj = z   + (size_t)N_NODES * DIM;

    char* ws = (char*)d_ws;
    size_t off = 0;
    auto walloc = [&](size_t bytes) -> void* {
        void* p = ws + off;
        off = (off + bytes + 255) & ~(size_t)255;
        return p;
    };
    const size_t PK_SHORTS = (size_t)RBT * 16 * 4096;
    unsigned short* Hb = (unsigned short*)walloc((size_t)N_NODES * DIM * sizeof(unsigned short));
    short* APKx  = (short*)walloc(PK_SHORTS * sizeof(short));
    short* ZPKp  = (short*)walloc(PK_SHORTS * sizeof(short));
    short* ZPKr  = (short*)walloc(PK_SHORTS * sizeof(short));
    short* APKp1 = (short*)walloc(PK_SHORTS * sizeof(short));
    short* WT1  = (short*)walloc((size_t)8 * 16 * 4096 * sizeof(short));
    short* WT2  = (short*)walloc((size_t)8 * 16 * 4096 * sizeof(short));
    short* WTp1 = (short*)walloc((size_t)8 * 16 * 4096 * sizeof(short));
    short* WTp2 = (short*)walloc((size_t)8 * 16 * 4096 * sizeof(short));
    int*   deg      = (int*)  walloc(N_NODES * sizeof(int));
    int*   cursor   = (int*)  walloc(N_NODES * sizeof(int));
    int*   row_off  = (int*)  walloc((N_NODES + 1) * sizeof(int));
    int*   bsum     = (int*)  walloc(SCAN_BLKS * sizeof(int));
    float* dis      = (float*)walloc(N_NODES * sizeof(float));
    int*   csr_src  = (int*)  walloc(N_EDGES * sizeof(int));
    float* csr_norm = (float*)walloc(N_EDGES * sizeof(float));

    const dim3 blk(256);
    const dim3 wave(64);

    packw_zero_kernel<<<dim3(512 + SCAN_BLKS), blk, 0, stream>>>(
        W1, W2, Wp1, Wp2, WT1, WT2, WTp1, WTp2, deg);
    packa_count_kernel<<<dim3(RBT * 16 + EBLKS), blk, 0, stream>>>(x, APKx, ei, deg);
    scan1_kernel<<<dim3(SCAN_BLKS), blk, 0, stream>>>(deg, row_off, bsum, dis, cursor, N_NODES);
    scan2_kernel<<<dim3(1), wave, 0, stream>>>(bsum);
    scan3_kernel<<<dim3(SCAN_BLKS), blk, 0, stream>>>(row_off, bsum, N_NODES);

    gemm1_scatter_kernel<<<dim3(GBLKS + EBLKS), blk, 0, stream>>>(
        APKx, WT1, b1, Hb, ei, dis, row_off, cursor, csr_src, csr_norm);
    agg1_pack_kernel<<<dim3(RB128 * 128), blk, 0, stream>>>(
        Hb, dis, row_off, csr_src, csr_norm, z, ZPKp, ZPKr);
    gemm23_kernel<<<dim3(2 * GBLKS), blk, 0, stream>>>(
        ZPKr, WT2, b2, Hb, ZPKp, WTp1, bp1, APKp1);
    agg2_kernel<<<dim3(N_NODES), blk, 0, stream>>>(Hb, dis, row_off, csr_src, csr_norm, out);
    gemm4_kernel<<<dim3(GBLKS), blk, 0, stream>>>(APKp1, WTp2, bp2, proj);
}

// Round 13
// 168.645 us; speedup vs baseline: 1.1788x; 1.1788x over previous
//
#include <hip/hip_runtime.h>
#include <stddef.h>

#define N_NODES 10000
#define N_EDGES 160000
#define DIM     512
#define RBT     158           // 64-row tiles incl. one zero pad tile (10112 rows)
#define RB128   79            // 128-row blocks
#define GBLKS   (RB128 * 4)   // 316 gemm blocks
#define SCAN_BLKS 40
#define EBLKS   625

typedef short bf16x8 __attribute__((ext_vector_type(8)));
typedef float f32x4  __attribute__((ext_vector_type(4)));

__device__ inline unsigned short bf16_rne(float f) {
    unsigned u = __builtin_bit_cast(unsigned, f);
    u += 0x7FFF + ((u >> 16) & 1);
    return (unsigned short)(u >> 16);
}
__device__ inline float bf16_to_f32(unsigned short h) {
    unsigned u = ((unsigned)h) << 16;
    return __builtin_bit_cast(float, u);
}

__device__ inline void gld_lds16(const void* g, void* lds) {
    __builtin_amdgcn_global_load_lds(
        (const __attribute__((address_space(1))) void*)g,
        (__attribute__((address_space(3))) void*)lds, 16, 0, 0);
}

// ================= pack weights (bf16, single plane) + zero deg =================
// Tile layout (shorts): [colblk64][kt 16][col 64][k 32], 2048/tile; XOR perm baked.

__global__ __launch_bounds__(256) void packw_zero_kernel(
    const float* __restrict__ W1, const float* __restrict__ W2,
    const float* __restrict__ Wp1, const float* __restrict__ Wp2,
    short* __restrict__ T1, short* __restrict__ T2,
    short* __restrict__ Tp1, short* __restrict__ Tp2,
    int* __restrict__ deg) {
    const int bid = blockIdx.x;
    if (bid >= 512) {
        int i = (bid - 512) * 256 + threadIdx.x;
        if (i < N_NODES) deg[i] = 0;
        return;
    }
    const int wsel = bid >> 7;
    const float* W = (wsel == 0) ? W1 : (wsel == 1) ? W2 : (wsel == 2) ? Wp1 : Wp2;
    short* WT      = (wsel == 0) ? T1 : (wsel == 1) ? T2 : (wsel == 2) ? Tp1 : Tp2;
    int id = (bid & 127) * 256 + threadIdx.x;
    int n  = id & 511;
    int kc = id >> 9;
    int colblk = n >> 6, col = n & 63;
    int kt = kc >> 2, kq = kc & 3;
    short hi[8];
#pragma unroll
    for (int j = 0; j < 8; ++j)
        hi[j] = (short)bf16_rne(W[(size_t)(kc * 8 + j) * 512 + n]);
    size_t base = (size_t)(colblk * 16 + kt) * 2048 + col * 32 + ((kq ^ ((col >> 1) & 3)) << 3);
    *(int4*)(WT + base) = *(const int4*)hi;
}

// ================= pack x (bf16) + count_deg =================

__global__ __launch_bounds__(256) void packa_count_kernel(
    const float* __restrict__ A, short* __restrict__ P0,
    const int* __restrict__ ei, int* __restrict__ deg) {
    const int bid = blockIdx.x;
    if (bid >= RBT * 16) {
        int e = (bid - RBT * 16) * 256 + threadIdx.x;
        if (e < N_EDGES) atomicAdd(&deg[ei[N_EDGES + e]], 1);
        return;
    }
    const int kt = bid & 15;
    const int rb = bid >> 4;
    const int t  = threadIdx.x;
    const int r  = t >> 2;
    const int kq = t & 3;
    const int row = rb * 64 + r;
    float v[8] = {};
    if (row < N_NODES) {
        float4 a = *(const float4*)(A + (size_t)row * 512 + kt * 32 + kq * 8);
        float4 b = *(const float4*)(A + (size_t)row * 512 + kt * 32 + kq * 8 + 4);
        v[0]=a.x; v[1]=a.y; v[2]=a.z; v[3]=a.w; v[4]=b.x; v[5]=b.y; v[6]=b.z; v[7]=b.w;
    }
    short hi[8];
#pragma unroll
    for (int j = 0; j < 8; ++j) hi[j] = (short)bf16_rne(v[j]);
    size_t base = (size_t)(rb * 16 + kt) * 2048 + r * 32 + ((kq ^ ((r >> 1) & 3)) << 3);
    *(int4*)(P0 + base) = *(const int4*)hi;
}

// ================= scans (verified) =================

__global__ __launch_bounds__(256) void scan1_kernel(const int* __restrict__ deg,
                                                    int* __restrict__ row_off,
                                                    int* __restrict__ bsum,
                                                    float* __restrict__ dis,
                                                    int* __restrict__ cursor, int n) {
    __shared__ int sm[256];
    const int i = blockIdx.x * 256 + threadIdx.x;
    int v = (i < n) ? deg[i] : 0;
    if (i < n) {
        dis[i] = rsqrtf((float)(v + 1));
        cursor[i] = 0;
    }
    sm[threadIdx.x] = v;
    __syncthreads();
    for (int off = 1; off < 256; off <<= 1) {
        int t = (threadIdx.x >= (unsigned)off) ? sm[threadIdx.x - off] : 0;
        __syncthreads();
        sm[threadIdx.x] += t;
        __syncthreads();
    }
    if (i < n) row_off[i + 1] = sm[threadIdx.x];
    if (threadIdx.x == 255) bsum[blockIdx.x] = sm[255];
}

__global__ __launch_bounds__(64) void scan2_kernel(int* __restrict__ bsum) {
    const int lane = threadIdx.x;
    int v0 = (lane < SCAN_BLKS) ? bsum[lane] : 0;
    int v = v0;
    for (int off = 1; off < 64; off <<= 1) {
        int t = __shfl_up(v, off, 64);
        if (lane >= off) v += t;
    }
    if (lane < SCAN_BLKS) bsum[lane] = v - v0;
}

__global__ __launch_bounds__(256) void scan3_kernel(int* __restrict__ row_off,
                                                    const int* __restrict__ bsum, int n) {
    const int i = blockIdx.x * 256 + threadIdx.x;
    if (i < n) row_off[i + 1] += bsum[blockIdx.x];
    if (i == 0) row_off[0] = 0;
}

// ================= 128x128 bf16 LDS-staged GEMM core =================
// 4 waves (2x2), glds double-buffer (32KB LDS -> ~4-5 blocks/CU), 1 barrier/kt.
// cb-major bijective XCD chunking.

__device__ __forceinline__ void map_block(int bid, int& rb, int& cb) {
    const int q = GBLKS / 8;      // 39
    const int r = GBLKS % 8;      // 4
    int xcd = bid & 7;
    int idx = bid >> 3;
    int L = (xcd < r ? xcd * (q + 1) : r * (q + 1) + (xcd - r) * q) + idx;
    cb = L / RB128;
    rb = L - cb * RB128;
}

__device__ __forceinline__ void gemm128_core(
    const short* __restrict__ Apk, const short* __restrict__ Wpk,
    int bid, f32x4 (&acc)[4][4],
    short (*As)[4096], short (*Bs)[4096],
    int& rb, int& cb, int& wr, int& wc)
{
    map_block(bid, rb, cb);
    const int tid = threadIdx.x;
    const int w = tid >> 6;
    wr = w >> 1;
    wc = w & 1;
    const int lane = tid & 63;
    const int l15 = lane & 15, kg = lane >> 4;
    const int kso = ((kg ^ ((l15 >> 1) & 3)) << 3);
    const int wofs = w * 1024;   // wave-uniform LDS byte offset within each 4KB chunk

    const char* At0 = (const char*)(Apk + (size_t)(rb * 2)     * 16 * 2048);
    const char* At1 = (const char*)(Apk + (size_t)(rb * 2 + 1) * 16 * 2048);
    const char* Bt0 = (const char*)(Wpk + (size_t)(cb * 2)     * 16 * 2048);
    const char* Bt1 = (const char*)(Wpk + (size_t)(cb * 2 + 1) * 16 * 2048);

#pragma unroll
    for (int i = 0; i < 4; ++i)
#pragma unroll
        for (int j = 0; j < 4; ++j) acc[i][j] = (f32x4){0.f, 0.f, 0.f, 0.f};

    // 4 glds per thread per stage (A0,A1,B0,B1 4KB chunks)
    auto stage = [&](int buf, int kt) {
        const int go = kt * 4096 + tid * 16;
        char* ad = (char*)&As[buf][0];
        char* bd = (char*)&Bs[buf][0];
        gld_lds16(At0 + go, ad + wofs);
        gld_lds16(At1 + go, ad + 4096 + wofs);
        gld_lds16(Bt0 + go, bd + wofs);
        gld_lds16(Bt1 + go, bd + 4096 + wofs);
    };

    stage(0, 0);
    __syncthreads();

#pragma unroll
    for (int kt = 0; kt < 16; ++kt) {
        const int buf = kt & 1;
        if (kt < 15) stage(buf ^ 1, kt + 1);

        const short* as = &As[buf][wr * 2048];
        const short* bs = &Bs[buf][wc * 2048];
        bf16x8 af[4], bf[4];
#pragma unroll
        for (int m = 0; m < 4; ++m)
            af[m] = *(const bf16x8*)&as[(m * 16 + l15) * 32 + kso];
#pragma unroll
        for (int n = 0; n < 4; ++n)
            bf[n] = *(const bf16x8*)&bs[(n * 16 + l15) * 32 + kso];
#pragma unroll
        for (int m = 0; m < 4; ++m)
#pragma unroll
            for (int n = 0; n < 4; ++n)
                acc[m][n] = __builtin_amdgcn_mfma_f32_16x16x32_bf16(af[m], bf[n], acc[m][n], 0, 0, 0);
        __syncthreads();
    }
}

// ---- epilogues (each wave writes its own 64x64 quarter) ----

template<bool RELU_OUT>
__device__ __forceinline__ void epi128_f32(f32x4 (&acc)[4][4], const float* bias,
                                           float* C, int rb, int cb, int wr, int wc) {
    const int lane = threadIdx.x & 63;
    const int l15 = lane & 15, kg = lane >> 4;
#pragma unroll
    for (int n = 0; n < 4; ++n) {
        int c = cb * 128 + wc * 64 + n * 16 + l15;
        float bv = bias[c];
#pragma unroll
        for (int m = 0; m < 4; ++m) {
            int r0 = rb * 128 + wr * 64 + m * 16 + kg * 4;
#pragma unroll
            for (int j = 0; j < 4; ++j) {
                int row = r0 + j;
                if (row < N_NODES) {
                    float v = acc[m][n][j] + bv;
                    if (RELU_OUT) v = fmaxf(v, 0.f);
                    C[(size_t)row * 512 + c] = v;
                }
            }
        }
    }
}

__device__ __forceinline__ void epi128_bf16(f32x4 (&acc)[4][4], const float* bias,
                                            unsigned short* C, int rb, int cb, int wr, int wc) {
    const int lane = threadIdx.x & 63;
    const int l15 = lane & 15, kg = lane >> 4;
#pragma unroll
    for (int n = 0; n < 4; ++n) {
        int c = cb * 128 + wc * 64 + n * 16 + l15;
        float bv = bias[c];
#pragma unroll
        for (int m = 0; m < 4; ++m) {
            int r0 = rb * 128 + wr * 64 + m * 16 + kg * 4;
#pragma unroll
            for (int j = 0; j < 4; ++j) {
                int row = r0 + j;
                if (row < N_NODES)
                    C[(size_t)row * 512 + c] = bf16_rne(acc[m][n][j] + bv);
            }
        }
    }
}

// relu(acc+bias) -> packed bf16 A-layout (row-tiles) for the next GEMM
__device__ __forceinline__ void epi128_pack(f32x4 (&acc)[4][4], const float* bias,
                                            short* Cpk, int rb, int cb, int wr, int wc) {
    const int lane = threadIdx.x & 63;
    const int l15 = lane & 15, kg = lane >> 4;
#pragma unroll
    for (int n = 0; n < 4; ++n) {
        int c = cb * 128 + wc * 64 + n * 16 + l15;   // = next-gemm k index
        int kt_n = c >> 5, kk = c & 31, kgn = kk >> 3, kj = kk & 7;
        float bv = bias[c];
#pragma unroll
        for (int m = 0; m < 4; ++m) {
#pragma unroll
            for (int j = 0; j < 4; ++j) {
                int grow = rb * 128 + wr * 64 + m * 16 + kg * 4 + j;   // <= 10111
                float v = (grow < N_NODES) ? fmaxf(acc[m][n][j] + bv, 0.f) : 0.f;
                int rt = grow >> 6, rl = grow & 63;
                size_t dst = (size_t)(rt * 16 + kt_n) * 2048 + rl * 32
                           + ((kgn ^ ((rl >> 1) & 3)) << 3) + kj;
                Cpk[dst] = (short)bf16_rne(v);
            }
        }
    }
}

// ================= fused GEMM1 + scatter =================

__global__ __launch_bounds__(256, 4) void gemm1_scatter_kernel(
    const short* __restrict__ APKx, const short* __restrict__ WT1,
    const float* __restrict__ b1, unsigned short* __restrict__ Hb,
    const int* __restrict__ ei, const float* __restrict__ dis,
    const int* __restrict__ row_off, int* __restrict__ cursor,
    int* __restrict__ csr_src, float* __restrict__ csr_norm)
{
    __shared__ short As[2][4096];
    __shared__ short Bs[2][4096];
    const int bid = blockIdx.x;
    if (bid >= GBLKS) {
        int e = (bid - GBLKS) * 256 + threadIdx.x;
        if (e < N_EDGES) {
            int s = ei[e];
            int d = ei[N_EDGES + e];
            int slot = row_off[d] + atomicAdd(&cursor[d], 1);
            csr_src[slot]  = s;
            csr_norm[slot] = dis[s] * dis[d];
        }
        return;
    }
    f32x4 acc[4][4];
    int rb, cb, wr, wc;
    gemm128_core(APKx, WT1, bid, acc, As, Bs, rb, cb, wr, wc);
    epi128_bf16(acc, b1, Hb, rb, cb, wr, wc);
}

// ================= aggregate1 + fused z-pack (grid 10112) =================

__global__ __launch_bounds__(256) void agg1_pack_kernel(
    const unsigned short* __restrict__ Hb,
    const float* __restrict__ dis,
    const int* __restrict__ row_off,
    const int* __restrict__ csr_src,
    const float* __restrict__ csr_norm,
    float* __restrict__ z,
    short* __restrict__ ZPKp, short* __restrict__ ZPKr)
{
    const int node = blockIdx.x;
    const int t = threadIdx.x;
    const int f0 = 2 * t;
    const int kt = f0 >> 5, kq = (f0 >> 3) & 3, j = f0 & 7;
    const int rb = node >> 6, r = node & 63;
    const size_t dst = (size_t)(rb * 16 + kt) * 2048 + r * 32 + ((kq ^ ((r >> 1) & 3)) << 3) + j;

    if (node >= N_NODES) {   // zero pad rows
        ushort2 zz = make_ushort2(0, 0);
        *(ushort2*)(ZPKp + dst) = zz;
        *(ushort2*)(ZPKr + dst) = zz;
        return;
    }

    const int start = row_off[node];
    const int end   = row_off[node + 1];
    const float dn = dis[node];
    const float sw = dn * dn;

    ushort2 hv = *((const ushort2*)(Hb + (size_t)node * DIM) + t);
    float a0 = bf16_to_f32(hv.x) * sw;
    float a1 = bf16_to_f32(hv.y) * sw;

    int e = start;
    for (; e + 3 < end; e += 4) {
        int s0 = csr_src[e],     s1 = csr_src[e + 1];
        int s2 = csr_src[e + 2], s3 = csr_src[e + 3];
        float w0 = csr_norm[e],     w1 = csr_norm[e + 1];
        float w2 = csr_norm[e + 2], w3 = csr_norm[e + 3];
        ushort2 v0 = *((const ushort2*)(Hb + (size_t)s0 * DIM) + t);
        ushort2 v1 = *((const ushort2*)(Hb + (size_t)s1 * DIM) + t);
        ushort2 v2 = *((const ushort2*)(Hb + (size_t)s2 * DIM) + t);
        ushort2 v3 = *((const ushort2*)(Hb + (size_t)s3 * DIM) + t);
        a0 += bf16_to_f32(v0.x) * w0 + bf16_to_f32(v1.x) * w1
            + bf16_to_f32(v2.x) * w2 + bf16_to_f32(v3.x) * w3;
        a1 += bf16_to_f32(v0.y) * w0 + bf16_to_f32(v1.y) * w1
            + bf16_to_f32(v2.y) * w2 + bf16_to_f32(v3.y) * w3;
    }
    for (; e < end; ++e) {
        int s = csr_src[e];
        float w = csr_norm[e];
        ushort2 v = *((const ushort2*)(Hb + (size_t)s * DIM) + t);
        a0 += bf16_to_f32(v.x) * w;
        a1 += bf16_to_f32(v.y) * w;
    }
    *((float2*)(z + (size_t)node * DIM) + t) = make_float2(a0, a1);

    *(ushort2*)(ZPKp + dst) = make_ushort2(bf16_rne(a0), bf16_rne(a1));
    *(ushort2*)(ZPKr + dst) = make_ushort2(bf16_rne(fmaxf(a0, 0.f)), bf16_rne(fmaxf(a1, 0.f)));
}

// ================= fused GEMM2 || GEMM3 =================

__global__ __launch_bounds__(256, 4) void gemm23_kernel(
    const short* __restrict__ ZPKr, const short* __restrict__ WT2,
    const float* __restrict__ b2, unsigned short* __restrict__ Hb,
    const short* __restrict__ ZPKp, const short* __restrict__ WTp1,
    const float* __restrict__ bp1, short* __restrict__ APKp1)
{
    __shared__ short As[2][4096];
    __shared__ short Bs[2][4096];
    const int bid = blockIdx.x;
    f32x4 acc[4][4];
    int rb, cb, wr, wc;
    if (bid < GBLKS) {
        gemm128_core(ZPKr, WT2, bid, acc, As, Bs, rb, cb, wr, wc);
        epi128_bf16(acc, b2, Hb, rb, cb, wr, wc);
    } else {
        gemm128_core(ZPKp, WTp1, bid - GBLKS, acc, As, Bs, rb, cb, wr, wc);
        epi128_pack(acc, bp1, APKp1, rb, cb, wr, wc);
    }
}

// ================= aggregate2 =================

__global__ __launch_bounds__(256) void agg2_kernel(
    const unsigned short* __restrict__ Hb, const float* __restrict__ dis,
    const int* __restrict__ row_off, const int* __restrict__ csr_src,
    const float* __restrict__ csr_norm, float* __restrict__ out)
{
    const int node = blockIdx.x;
    const int t = threadIdx.x;
    const int start = row_off[node];
    const int end   = row_off[node + 1];
    const float dn = dis[node];
    const float sw = dn * dn;

    ushort2 hv = *((const ushort2*)(Hb + (size_t)node * DIM) + t);
    float a0 = bf16_to_f32(hv.x) * sw;
    float a1 = bf16_to_f32(hv.y) * sw;

    int e = start;
    for (; e + 3 < end; e += 4) {
        int s0 = csr_src[e],     s1 = csr_src[e + 1];
        int s2 = csr_src[e + 2], s3 = csr_src[e + 3];
        float w0 = csr_norm[e],     w1 = csr_norm[e + 1];
        float w2 = csr_norm[e + 2], w3 = csr_norm[e + 3];
        ushort2 v0 = *((const ushort2*)(Hb + (size_t)s0 * DIM) + t);
        ushort2 v1 = *((const ushort2*)(Hb + (size_t)s1 * DIM) + t);
        ushort2 v2 = *((const ushort2*)(Hb + (size_t)s2 * DIM) + t);
        ushort2 v3 = *((const ushort2*)(Hb + (size_t)s3 * DIM) + t);
        a0 += bf16_to_f32(v0.x) * w0 + bf16_to_f32(v1.x) * w1
            + bf16_to_f32(v2.x) * w2 + bf16_to_f32(v3.x) * w3;
        a1 += bf16_to_f32(v0.y) * w0 + bf16_to_f32(v1.y) * w1
            + bf16_to_f32(v2.y) * w2 + bf16_to_f32(v3.y) * w3;
    }
    for (; e < end; ++e) {
        int s = csr_src[e];
        float w = csr_norm[e];
        ushort2 v = *((const ushort2*)(Hb + (size_t)s * DIM) + t);
        a0 += bf16_to_f32(v.x) * w;
        a1 += bf16_to_f32(v.y) * w;
    }
    *((float2*)(out + (size_t)node * DIM) + t) = make_float2(a0, a1);
}

// ================= GEMM4 =================

__global__ __launch_bounds__(256, 4) void gemm4_kernel(
    const short* __restrict__ APKp1, const short* __restrict__ WTp2,
    const float* __restrict__ bp2, float* __restrict__ proj)
{
    __shared__ short As[2][4096];
    __shared__ short Bs[2][4096];
    f32x4 acc[4][4];
    int rb, cb, wr, wc;
    gemm128_core(APKp1, WTp2, blockIdx.x, acc, As, Bs, rb, cb, wr, wc);
    epi128_f32<false>(acc, bp2, proj, rb, cb, wr, wc);
}

// ================= launch =================

extern "C" void kernel_launch(void* const* d_in, const int* in_sizes, int n_in,
                              void* d_out, int out_size, void* d_ws, size_t ws_size,
                              hipStream_t stream) {
    const float* x   = (const float*)d_in[0];
    const int*   ei  = (const int*)d_in[1];
    const float* W1  = (const float*)d_in[2];
    const float* b1  = (const float*)d_in[3];
    const float* W2  = (const float*)d_in[4];
    const float* b2  = (const float*)d_in[5];
    const float* Wp1 = (const float*)d_in[6];
    const float* bp1 = (const float*)d_in[7];
    const float* Wp2 = (const float*)d_in[8];
    const float* bp2 = (const float*)d_in[9];

    float* out  = (float*)d_out;
    float* z    = out + (size_t)N_NODES * DIM;
    float* proj = z   + (size_t)N_NODES * DIM;

    char* ws = (char*)d_ws;
    size_t off = 0;
    auto walloc = [&](size_t bytes) -> void* {
        void* p = ws + off;
        off = (off + bytes + 255) & ~(size_t)255;
        return p;
    };
    const size_t PK_SHORTS = (size_t)RBT * 16 * 2048;   // 5.17M shorts = 10.35 MB
    unsigned short* Hb = (unsigned short*)walloc((size_t)N_NODES * DIM * sizeof(unsigned short));
    short* APKx  = (short*)walloc(PK_SHORTS * sizeof(short));
    short* ZPKp  = (short*)walloc(PK_SHORTS * sizeof(short));
    short* ZPKr  = (short*)walloc(PK_SHORTS * sizeof(short));
    short* APKp1 = (short*)walloc(PK_SHORTS * sizeof(short));
    short* WT1  = (short*)walloc((size_t)8 * 16 * 2048 * sizeof(short));
    short* WT2  = (short*)walloc((size_t)8 * 16 * 2048 * sizeof(short));
    short* WTp1 = (short*)walloc((size_t)8 * 16 * 2048 * sizeof(short));
    short* WTp2 = (short*)walloc((size_t)8 * 16 * 2048 * sizeof(short));
    int*   deg      = (int*)  walloc(N_NODES * sizeof(int));
    int*   cursor   = (int*)  walloc(N_NODES * sizeof(int));
    int*   row_off  = (int*)  walloc((N_NODES + 1) * sizeof(int));
    int*   bsum     = (int*)  walloc(SCAN_BLKS * sizeof(int));
    float* dis      = (float*)walloc(N_NODES * sizeof(float));
    int*   csr_src  = (int*)  walloc(N_EDGES * sizeof(int));
    float* csr_norm = (float*)walloc(N_EDGES * sizeof(float));

    const dim3 blk(256);
    const dim3 wave(64);

    packw_zero_kernel<<<dim3(512 + SCAN_BLKS), blk, 0, stream>>>(
        W1, W2, Wp1, Wp2, WT1, WT2, WTp1, WTp2, deg);
    packa_count_kernel<<<dim3(RBT * 16 + EBLKS), blk, 0, stream>>>(x, APKx, ei, deg);
    scan1_kernel<<<dim3(SCAN_BLKS), blk, 0, stream>>>(deg, row_off, bsum, dis, cursor, N_NODES);
    scan2_kernel<<<dim3(1), wave, 0, stream>>>(bsum);
    scan3_kernel<<<dim3(SCAN_BLKS), blk, 0, stream>>>(row_off, bsum, N_NODES);

    gemm1_scatter_kernel<<<dim3(GBLKS + EBLKS), blk, 0, stream>>>(
        APKx, WT1, b1, Hb, ei, dis, row_off, cursor, csr_src, csr_norm);
    agg1_pack_kernel<<<dim3(RB128 * 128), blk, 0, stream>>>(
        Hb, dis, row_off, csr_src, csr_norm, z, ZPKp, ZPKr);
    gemm23_kernel<<<dim3(2 * GBLKS), blk, 0, stream>>>(
        ZPKr, WT2, b2, Hb, ZPKp, WTp1, bp1, APKp1);
    agg2_kernel<<<dim3(N_NODES), blk, 0, stream>>>(Hb, dis, row_off, csr_src, csr_norm, out);
    gemm4_kernel<<<dim3(GBLKS), blk, 0, stream>>>(APKp1, WTp2, bp2, proj);
}